// Round 2
// baseline (402.808 us; speedup 1.0000x reference)
//
#include <hip/hip_runtime.h>
#include <hip/hip_bf16.h>

#define N_NODES 100000
#define N_EDGES 1600000
#define N_ROIS  400
#define RKP     416      // 400 padded to 13*32
#define HID     128
#define N_GRAPHS 512
#define NOUT    2
#define NBUCK   391      // ceil(N_NODES/256), bucket = node >> 8
#define BCAP    8192     // per-bucket edge capacity (mean 4092, sigma 64)
#define ECH     4096     // edges per bucket_k block
#define NPW     8        // nodes per gather wave (was 16: grid too small, occ 54%)

typedef __attribute__((ext_vector_type(8))) short short8;
typedef __attribute__((ext_vector_type(4))) float f32x4;

static __device__ __forceinline__ unsigned short f2bf(float f) {
  unsigned u = __float_as_uint(f);
  u += 0x7fffu + ((u >> 16) & 1u);   // RNE
  return (unsigned short)(u >> 16);
}
static __device__ __forceinline__ float bf2f(unsigned short h) {
  return __uint_as_float(((unsigned)h) << 16);
}

static __device__ __forceinline__ void gload_lds16(const unsigned short* g, short* l) {
  __builtin_amdgcn_global_load_lds(
      (const __attribute__((address_space(1))) void*)g,
      (__attribute__((address_space(3))) void*)l, 16, 0, 0);
}

// ---- single-pass bucket append: pairs[b*BCAP + rank] = (row<<8 | col&255) ----
__global__ __launch_bounds__(256) void bucket_k(
    const int* __restrict__ row, const int* __restrict__ col,
    int* __restrict__ bcnt, unsigned int* __restrict__ pairs) {
  __shared__ int hist[NBUCK];
  __shared__ int base[NBUCK];
  int t = threadIdx.x;
  for (int b = t; b < NBUCK; b += 256) hist[b] = 0;
  __syncthreads();
  int e0 = blockIdx.x * ECH;
  unsigned int pk[16];
  int bk[16], rk[16];
#pragma unroll
  for (int i = 0; i < 16; ++i) {
    int e = e0 + t + i * 256;
    if (e < N_EDGES) {
      int r = row[e], c = col[e];
      bk[i] = c >> 8;
      pk[i] = ((unsigned)r << 8) | (unsigned)(c & 255);
      rk[i] = atomicAdd(&hist[bk[i]], 1);   // LDS atomic: local rank
    } else bk[i] = -1;
  }
  __syncthreads();
  for (int b = t; b < NBUCK; b += 256)
    base[b] = (hist[b] > 0) ? atomicAdd(&bcnt[b], hist[b]) : 0;
  __syncthreads();
#pragma unroll
  for (int i = 0; i < 16; ++i)
    if (bk[i] >= 0) {
      int p = base[bk[i]] + rk[i];
      if (p < BCAP) pairs[(size_t)bk[i] * BCAP + p] = pk[i];
    }
}

// ---- per-bucket CSR build in LDS; per-node offsets padded to multiples of 4
//      so gather_k can read edge indices with aligned int4 loads ----
__global__ __launch_bounds__(256) void csr_build_k(
    const unsigned int* __restrict__ pairs, const int* __restrict__ bcnt,
    int* __restrict__ csr_row, int* __restrict__ offs, int* __restrict__ cnt,
    float* __restrict__ dinv) {
  __shared__ unsigned int ep[BCAP];
  __shared__ int h[256];
  __shared__ int sc[256];
  __shared__ int cur[256];
  int b = blockIdx.x;
  int t = threadIdx.x;
  int m = min(bcnt[b], BCAP);
  size_t base = (size_t)b * BCAP;
  for (int j = t; j < m; j += 256) ep[j] = pairs[base + j];
  h[t] = 0;
  __syncthreads();
  for (int j = t; j < m; j += 256) atomicAdd(&h[ep[j] & 255u], 1);
  __syncthreads();
  int myc = h[t];
  int mycp = (myc + 3) & ~3;          // pad each node's slot to multiple of 4
  sc[t] = mycp;
  __syncthreads();
  for (int off = 1; off < 256; off <<= 1) {
    int v = (t >= off) ? sc[t - off] : 0;
    __syncthreads();
    sc[t] += v;
    __syncthreads();
  }
  int loff = sc[t] - mycp;            // padded exclusive scan (multiple of 4)
  cur[t] = loff;
  int node = b * 256 + t;
  if (node < N_NODES) {
    cnt[node] = myc;
    offs[node] = (int)base + loff;
    dinv[node] = rsqrtf((float)(myc + 1));
  }
  __syncthreads();
  for (int j = t; j < m; j += 256) {
    unsigned int e = ep[j];
    int pos = atomicAdd(&cur[e & 255u], 1);   // LDS atomic
    if (pos < BCAP) csr_row[base + pos] = (int)(e >> 8);
  }
}

// ---- W [400][128] fp32 -> Wf bf16 in MFMA fragment order ----
__global__ void prep_wt_k(const float* __restrict__ W, unsigned short* __restrict__ Wf) {
  int idx = blockIdx.x * blockDim.x + threadIdx.x;
  if (idx >= 13 * 8 * 64 * 8) return;
  int u    = idx & 7;
  int lane = (idx >> 3) & 63;
  int nt   = (idx >> 9) & 7;
  int kk5  = idx >> 12;
  int n = nt * 16 + (lane & 15);
  int k = kk5 * 32 + (lane >> 4) * 8 + u;
  Wf[idx] = (k < N_ROIS) ? f2bf(W[k * HID + n]) : (unsigned short)0;
}

// ---- h' = (x@W) * dinv[row]: B resident in LDS, A straight to registers ----
__global__ __launch_bounds__(512, 4) void gemm_k(
    const float* __restrict__ x, const unsigned short* __restrict__ Wf,
    const float* __restrict__ dinv, unsigned short* __restrict__ hp) {
  __shared__ __align__(16) short Bs[28672];   // 57,344 B: 7 K-steps x 8 nt x 1 KB
  int t = threadIdx.x;
  int lane = t & 63, wv = t >> 6;
  int mrow = lane & 15, kg = lane >> 4;
  int row0 = blockIdx.x * 128;
  int arow = row0 + wv * 16 + mrow;
  bool rowok = arow < N_NODES;
  const float* xp = x + (size_t)arow * N_ROIS;

  f32x4 acc[8];
#pragma unroll
  for (int i = 0; i < 8; ++i) acc[i] = (f32x4){0.f, 0.f, 0.f, 0.f};

  // stage phase A: K-steps 0..6
#pragma unroll
  for (int c = 0; c < 7; ++c) {
    int ch = wv * 7 + c;
    gload_lds16(Wf + (size_t)ch * 512 + lane * 8, &Bs[ch * 512]);
  }
  asm volatile("s_waitcnt vmcnt(0)" ::: "memory");
  __syncthreads();

#pragma unroll
  for (int kf = 0; kf < 7; ++kf) {
    int k0 = kf * 32 + kg * 8;
    short8 a8;
    if (rowok && k0 + 8 <= N_ROIS) {
      float4 f0 = *(const float4*)(xp + k0);
      float4 f1 = *(const float4*)(xp + k0 + 4);
      a8[0] = (short)f2bf(f0.x); a8[1] = (short)f2bf(f0.y);
      a8[2] = (short)f2bf(f0.z); a8[3] = (short)f2bf(f0.w);
      a8[4] = (short)f2bf(f1.x); a8[5] = (short)f2bf(f1.y);
      a8[6] = (short)f2bf(f1.z); a8[7] = (short)f2bf(f1.w);
    } else {
#pragma unroll
      for (int u = 0; u < 8; ++u) {
        int k = k0 + u;
        float f = (rowok && k < N_ROIS) ? xp[k] : 0.f;
        a8[u] = (short)f2bf(f);
      }
    }
#pragma unroll
    for (int nt = 0; nt < 8; ++nt) {
      short8 bf = *(const short8*)&Bs[(kf * 8 + nt) * 512 + lane * 8];
      acc[nt] = __builtin_amdgcn_mfma_f32_16x16x32_bf16(a8, bf, acc[nt], 0, 0, 0);
    }
  }
  __syncthreads();

  // stage phase B: K-steps 7..12
#pragma unroll
  for (int c = 0; c < 6; ++c) {
    int ch = wv * 6 + c;
    gload_lds16(Wf + (size_t)(56 + ch) * 512 + lane * 8, &Bs[ch * 512]);
  }
  asm volatile("s_waitcnt vmcnt(0)" ::: "memory");
  __syncthreads();

#pragma unroll
  for (int kf = 0; kf < 6; ++kf) {
    int k0 = (kf + 7) * 32 + kg * 8;
    short8 a8;
    if (rowok && k0 + 8 <= N_ROIS) {
      float4 f0 = *(const float4*)(xp + k0);
      float4 f1 = *(const float4*)(xp + k0 + 4);
      a8[0] = (short)f2bf(f0.x); a8[1] = (short)f2bf(f0.y);
      a8[2] = (short)f2bf(f0.z); a8[3] = (short)f2bf(f0.w);
      a8[4] = (short)f2bf(f1.x); a8[5] = (short)f2bf(f1.y);
      a8[6] = (short)f2bf(f1.z); a8[7] = (short)f2bf(f1.w);
    } else {
#pragma unroll
      for (int u = 0; u < 8; ++u) {
        int k = k0 + u;
        float f = (rowok && k < N_ROIS) ? xp[k] : 0.f;
        a8[u] = (short)f2bf(f);
      }
    }
#pragma unroll
    for (int nt = 0; nt < 8; ++nt) {
      short8 bf = *(const short8*)&Bs[(kf * 8 + nt) * 512 + lane * 8];
      acc[nt] = __builtin_amdgcn_mfma_f32_16x16x32_bf16(a8, bf, acc[nt], 0, 0, 0);
    }
  }

#pragma unroll
  for (int r = 0; r < 4; ++r) {
    int grow = row0 + wv * 16 + kg * 4 + r;
    if (grow < N_NODES) {
      float di = dinv[grow];
      unsigned short* op = hp + (size_t)grow * HID + mrow;
#pragma unroll
      for (int nt = 0; nt < 8; ++nt) op[nt * 16] = f2bf(di * acc[nt][r]);
    }
  }
}

static __device__ __forceinline__ void acc8(float* a, uint4 u) {
  a[0] += bf2f((unsigned short)(u.x));
  a[1] += bf2f((unsigned short)(u.x >> 16));
  a[2] += bf2f((unsigned short)(u.y));
  a[3] += bf2f((unsigned short)(u.y >> 16));
  a[4] += bf2f((unsigned short)(u.z));
  a[5] += bf2f((unsigned short)(u.z >> 16));
  a[6] += bf2f((unsigned short)(u.w));
  a[7] += bf2f((unsigned short)(u.w >> 16));
}

// ---- aggregation: 16 lanes per edge-slot; 16 edges (4 int4 groups) batched
//      per dependence chain -> 4 independent hp dwordx4 loads in flight/lane ----
__global__ __launch_bounds__(256) void gather_k(
    const unsigned short* __restrict__ hp, const int* __restrict__ csr_row,
    const int* __restrict__ offs, const int* __restrict__ cnt,
    const float* __restrict__ dinv, const int* __restrict__ batch,
    const float* __restrict__ bias, unsigned int* __restrict__ pooled_bits) {
  int wave = (blockIdx.x * blockDim.x + threadIdx.x) >> 6;
  int lane = threadIdx.x & 63;
  int g  = lane >> 4;        // edge-slot group 0..3
  int cg = lane & 15;        // column group: cols cg*8 .. cg*8+7
  int n0 = wave * NPW;
  if (n0 >= N_NODES) return;
  int nend = min(n0 + NPW, N_NODES);
  float bv[8];
  {
    float4 b0 = *(const float4*)(bias + cg * 8);
    float4 b1 = *(const float4*)(bias + cg * 8 + 4);
    bv[0] = b0.x; bv[1] = b0.y; bv[2] = b0.z; bv[3] = b0.w;
    bv[4] = b1.x; bv[5] = b1.y; bv[6] = b1.z; bv[7] = b1.w;
  }
  float rm[8];
#pragma unroll
  for (int k = 0; k < 8; ++k) rm[k] = 0.f;   // relu >= 0 -> 0 is identity
  int cur_g = batch[n0];

  for (int i = n0; i < nend; ++i) {
    int start = offs[i];
    int m = cnt[i];
    const int* cp = csr_row + start;
    float a[8];
#pragma unroll
    for (int k = 0; k < 8; ++k) a[k] = 0.f;
    if (g == 0) {                         // self row (deg includes self-loop)
      uint4 u = *(const uint4*)(hp + (size_t)i * HID + cg * 8);
      acc8(a, u);
    }
    // 16 edges per iteration: 4 independent csr int4 reads (always safe:
    // padded slots stay inside the bucket), 4 guarded hp dwordx4 in flight
    for (int j = 0; j < m; j += 16) {
      int4 q0 = *(const int4*)(cp + j);
      int4 q1 = *(const int4*)(cp + j + 4);
      int4 q2 = *(const int4*)(cp + j + 8);
      int4 q3 = *(const int4*)(cp + j + 12);
      int s0 = (g == 0) ? q0.x : (g == 1) ? q0.y : (g == 2) ? q0.z : q0.w;
      int s1 = (g == 0) ? q1.x : (g == 1) ? q1.y : (g == 2) ? q1.z : q1.w;
      int s2 = (g == 0) ? q2.x : (g == 1) ? q2.y : (g == 2) ? q2.z : q2.w;
      int s3 = (g == 0) ? q3.x : (g == 1) ? q3.y : (g == 2) ? q3.z : q3.w;
      bool c0 = (j      + g) < m;
      bool c1 = (j + 4  + g) < m;
      bool c2 = (j + 8  + g) < m;
      bool c3 = (j + 12 + g) < m;
      uint4 u0, u1, u2, u3;
      if (c0) u0 = *(const uint4*)(hp + (size_t)s0 * HID + cg * 8);
      if (c1) u1 = *(const uint4*)(hp + (size_t)s1 * HID + cg * 8);
      if (c2) u2 = *(const uint4*)(hp + (size_t)s2 * HID + cg * 8);
      if (c3) u3 = *(const uint4*)(hp + (size_t)s3 * HID + cg * 8);
      if (c0) acc8(a, u0);
      if (c1) acc8(a, u1);
      if (c2) acc8(a, u2);
      if (c3) acc8(a, u3);
    }
    // butterfly: sum the 4 edge-slot groups (lanes l, l^16, l^32, l^48)
#pragma unroll
    for (int k = 0; k < 8; ++k) {
      a[k] += __shfl_xor(a[k], 16);
      a[k] += __shfl_xor(a[k], 32);
    }
    float di = dinv[i];
    int gb = batch[i];
    if (gb != cur_g) {                    // wave-uniform branch
      if (lane < 16) {
#pragma unroll
        for (int k = 0; k < 8; ++k)
          atomicMax(&pooled_bits[cur_g * HID + cg * 8 + k], __float_as_uint(rm[k]));
      }
#pragma unroll
      for (int k = 0; k < 8; ++k) rm[k] = 0.f;
      cur_g = gb;
    }
#pragma unroll
    for (int k = 0; k < 8; ++k)
      rm[k] = fmaxf(rm[k], fmaxf(fmaf(di, a[k], bv[k]), 0.f));
  }
  if (lane < 16) {
#pragma unroll
    for (int k = 0; k < 8; ++k)
      atomicMax(&pooled_bits[cur_g * HID + cg * 8 + k], __float_as_uint(rm[k]));
  }
}

// ---- logits = pooled @ lin_W + lin_b ----
__global__ void logits_k(const float* __restrict__ pooled, const float* __restrict__ lin_W,
                         const float* __restrict__ lin_b, float* __restrict__ out) {
  int t = blockIdx.x * blockDim.x + threadIdx.x;
  if (t < N_GRAPHS * NOUT) {
    int g = t >> 1, o = t & 1;
    float s = lin_b[o];
    const float* pg = pooled + g * HID;
#pragma unroll 8
    for (int k = 0; k < HID; ++k) s = fmaf(pg[k], lin_W[k * NOUT + o], s);
    out[t] = s;
  }
}

extern "C" void kernel_launch(void* const* d_in, const int* in_sizes, int n_in,
                              void* d_out, int out_size, void* d_ws, size_t ws_size,
                              hipStream_t stream) {
  (void)in_sizes; (void)n_in; (void)ws_size;
  const float* x     = (const float*)d_in[0];
  const int*   ei    = (const int*)d_in[1];
  const int*   row   = ei;             // sources
  const int*   col   = ei + N_EDGES;   // targets
  const int*   batch = (const int*)d_in[2];
  const float* W     = (const float*)d_in[3];
  const float* b     = (const float*)d_in[4];
  const float* lin_W = (const float*)d_in[5];
  const float* lin_b = (const float*)d_in[6];
  float* out = (float*)d_out;

  // workspace layout (39.73 MB total; pairs dead after csr_build_k -> hp aliases it)
  char* ws = (char*)d_ws;
  int*   bcnt    = (int*)(ws + 0);               //   4,096 B (391 used)
  int*   offs    = (int*)(ws + 4096);            // 400,000 B
  int*   cnt     = (int*)(ws + 404096);          // 400,000 B
  float* dinv    = (float*)(ws + 804096);        // 400,000 B
  unsigned short* Wf = (unsigned short*)(ws + 1204096);   // 106,496 B (frag order)
  int*   csr_row = (int*)(ws + 1310720);         // 391*8192*4 = 12,812,288 B
  unsigned int* pairs = (unsigned int*)(ws + 14123008);   // 12,812,288 B
  unsigned short* hp  = (unsigned short*)(ws + 14123008); // 25,600,000 B (aliases pairs)

  hipMemsetAsync(bcnt, 0, NBUCK * sizeof(int), stream);
  hipMemsetAsync(d_out, 0, (size_t)out_size * sizeof(float), stream);

  bucket_k<<<(N_EDGES + ECH - 1) / ECH, 256, 0, stream>>>(row, col, bcnt, pairs);
  csr_build_k<<<NBUCK, 256, 0, stream>>>(pairs, bcnt, csr_row, offs, cnt, dinv);
  prep_wt_k<<<(13 * 8 * 64 * 8 + 255) / 256, 256, 0, stream>>>(W, Wf);
  gemm_k<<<(N_NODES + 127) / 128, 512, 0, stream>>>(x, Wf, dinv, hp);
  {
    int waves = (N_NODES + NPW - 1) / NPW;             // 12500
    int blocks = (waves * 64 + 255) / 256;             // 3125
    gather_k<<<blocks, 256, 0, stream>>>(
        hp, csr_row, offs, cnt, dinv, batch, b,
        (unsigned int*)(out + N_GRAPHS * NOUT));
  }
  logits_k<<<(N_GRAPHS * NOUT + 255) / 256, 256, 0, stream>>>(
      out + N_GRAPHS * NOUT, lin_W, lin_b, out);
}

// Round 3
// 385.519 us; speedup vs baseline: 1.0448x; 1.0448x over previous
//
#include <hip/hip_runtime.h>
#include <hip/hip_bf16.h>

#define N_NODES 100000
#define N_EDGES 1600000
#define N_ROIS  400
#define HID     128
#define N_GRAPHS 512
#define NOUT    2
#define NBUCK   391      // ceil(N_NODES/256), bucket = node >> 8
#define BCAP    8192     // per-bucket edge capacity (mean 4092, 64 sigma margin)
#define ECH     4096     // edges per bucket block
#define NPW     16       // nodes per gather wave (NPW=8 was a measured regression)
#define NBLK_BUCKET 391  // ceil(N_EDGES/ECH)
#define NBLK_PREP   208  // 13*8*64*8 / 256
#define NBLK_GEMM   782  // ceil(N_NODES/128)

typedef __attribute__((ext_vector_type(8))) short short8;
typedef __attribute__((ext_vector_type(4))) float f32x4;

static __device__ __forceinline__ unsigned short f2bf(float f) {
  unsigned u = __float_as_uint(f);
  u += 0x7fffu + ((u >> 16) & 1u);   // RNE
  return (unsigned short)(u >> 16);
}
static __device__ __forceinline__ float bf2f(unsigned short h) {
  return __uint_as_float(((unsigned)h) << 16);
}

static __device__ __forceinline__ void gload_lds16(const unsigned short* g, short* l) {
  __builtin_amdgcn_global_load_lds(
      (const __attribute__((address_space(1))) void*)g,
      (__attribute__((address_space(3))) void*)l, 16, 0, 0);
}

// ==== L1 fused: blocks [0,391) bucket-append, [391,599) Wf fragment pack ====
// bucket: pairs[b*BCAP + rank] = (row<<8 | col&255)
// prep:   Wf[((kk5*8+nt)*64+lane)*8+u] = bf16(W[k][n]), MFMA fragment order
__global__ __launch_bounds__(256) void prep_bucket_k(
    const int* __restrict__ row, const int* __restrict__ col,
    int* __restrict__ bcnt, unsigned int* __restrict__ pairs,
    const float* __restrict__ W, unsigned short* __restrict__ Wf) {
  __shared__ int hist[NBUCK];
  __shared__ int base[NBUCK];
  int t = threadIdx.x;
  if (blockIdx.x >= NBLK_BUCKET) {
    int idx = (blockIdx.x - NBLK_BUCKET) * 256 + t;
    if (idx < 13 * 8 * 64 * 8) {
      int u    = idx & 7;
      int lane = (idx >> 3) & 63;
      int nt   = (idx >> 9) & 7;
      int kk5  = idx >> 12;
      int n = nt * 16 + (lane & 15);
      int k = kk5 * 32 + (lane >> 4) * 8 + u;
      Wf[idx] = (k < N_ROIS) ? f2bf(W[k * HID + n]) : (unsigned short)0;
    }
    return;
  }
  for (int b = t; b < NBUCK; b += 256) hist[b] = 0;
  __syncthreads();
  int e0 = blockIdx.x * ECH;
  unsigned int pk[16];
  int bk[16], rk[16];
#pragma unroll
  for (int i = 0; i < 16; ++i) {
    int e = e0 + t + i * 256;
    if (e < N_EDGES) {
      int r = row[e], c = col[e];
      bk[i] = c >> 8;
      pk[i] = ((unsigned)r << 8) | (unsigned)(c & 255);
      rk[i] = atomicAdd(&hist[bk[i]], 1);   // LDS atomic: local rank
    } else bk[i] = -1;
  }
  __syncthreads();
  for (int b = t; b < NBUCK; b += 256)
    base[b] = (hist[b] > 0) ? atomicAdd(&bcnt[b], hist[b]) : 0;
  __syncthreads();
#pragma unroll
  for (int i = 0; i < 16; ++i)
    if (bk[i] >= 0) {
      int p = base[bk[i]] + rk[i];
      if (p < BCAP) pairs[(size_t)bk[i] * BCAP + p] = pk[i];
    }
}

// ==== L2 fused: blocks [0,391) per-bucket CSR build, [391,1173) GEMM ====
// Legal because: gemm no longer reads dinv (source-side dinv moved to gather),
// and hp no longer aliases pairs. csr blocks dispatch first, gemm fills the CUs.
__global__ __launch_bounds__(512, 4) void csr_gemm_k(
    const unsigned int* __restrict__ pairs, const int* __restrict__ bcnt,
    int* __restrict__ csr_row, int* __restrict__ offs, int* __restrict__ cnt,
    float* __restrict__ dinv,
    const float* __restrict__ x, const unsigned short* __restrict__ Wf,
    unsigned short* __restrict__ hp) {
  __shared__ __align__(16) union {
    struct { unsigned int ep[BCAP]; int h[256]; int sc[256]; int cur[256]; } c; // 35.8 KB
    short Bs[28672];                                                            // 57.3 KB
  } u;
  int t = threadIdx.x;

  if (blockIdx.x < NBUCK) {
    // ---- CSR branch: 512 threads, per-node work on t<256, uniform barriers ----
    bool act = t < 256;
    int b = blockIdx.x;
    int m = min(bcnt[b], BCAP);
    size_t base = (size_t)b * BCAP;
    for (int j = t; j < m; j += 512) u.c.ep[j] = pairs[base + j];
    if (act) u.c.h[t] = 0;
    __syncthreads();
    for (int j = t; j < m; j += 512) atomicAdd(&u.c.h[u.c.ep[j] & 255u], 1);
    __syncthreads();
    int myc = act ? u.c.h[t] : 0;
    int mycp = (myc + 3) & ~3;          // pad slot to multiple of 4 (int4 reads)
    if (act) u.c.sc[t] = mycp;
    __syncthreads();
    for (int off = 1; off < 256; off <<= 1) {
      int v = (act && t >= off) ? u.c.sc[t - off] : 0;
      __syncthreads();
      if (act) u.c.sc[t] += v;
      __syncthreads();
    }
    if (act) {
      int loff = u.c.sc[t] - mycp;      // padded exclusive scan
      u.c.cur[t] = loff;
      int node = b * 256 + t;
      if (node < N_NODES) {
        cnt[node] = myc;
        offs[node] = (int)base + loff;
        dinv[node] = rsqrtf((float)(myc + 1));
      }
    }
    __syncthreads();
    for (int j = t; j < m; j += 512) {
      unsigned int e = u.c.ep[j];
      int pos = atomicAdd(&u.c.cur[e & 255u], 1);   // LDS atomic
      if (pos < BCAP) csr_row[base + pos] = (int)(e >> 8);
    }
    return;
  }

  // ---- GEMM branch: hp = bf16(x @ W), NO dinv scaling (moved to gather) ----
  int lane = t & 63, wv = t >> 6;
  int mrow = lane & 15, kg = lane >> 4;
  int row0 = (blockIdx.x - NBUCK) * 128;
  int arow = row0 + wv * 16 + mrow;
  bool rowok = arow < N_NODES;
  const float* xp = x + (size_t)arow * N_ROIS;

  f32x4 acc[8];
#pragma unroll
  for (int i = 0; i < 8; ++i) acc[i] = (f32x4){0.f, 0.f, 0.f, 0.f};

  // stage phase A: K-steps 0..6 (7 x 1KB chunks per wave)
#pragma unroll
  for (int c = 0; c < 7; ++c) {
    int ch = wv * 7 + c;
    gload_lds16(Wf + (size_t)ch * 512 + lane * 8, &u.Bs[ch * 512]);
  }
  asm volatile("s_waitcnt vmcnt(0)" ::: "memory");
  __syncthreads();

#pragma unroll
  for (int kf = 0; kf < 7; ++kf) {
    int k0 = kf * 32 + kg * 8;
    short8 a8;
    if (rowok && k0 + 8 <= N_ROIS) {
      float4 f0 = *(const float4*)(xp + k0);
      float4 f1 = *(const float4*)(xp + k0 + 4);
      a8[0] = (short)f2bf(f0.x); a8[1] = (short)f2bf(f0.y);
      a8[2] = (short)f2bf(f0.z); a8[3] = (short)f2bf(f0.w);
      a8[4] = (short)f2bf(f1.x); a8[5] = (short)f2bf(f1.y);
      a8[6] = (short)f2bf(f1.z); a8[7] = (short)f2bf(f1.w);
    } else {
#pragma unroll
      for (int v = 0; v < 8; ++v) {
        int k = k0 + v;
        float f = (rowok && k < N_ROIS) ? xp[k] : 0.f;
        a8[v] = (short)f2bf(f);
      }
    }
#pragma unroll
    for (int nt = 0; nt < 8; ++nt) {
      short8 bf = *(const short8*)&u.Bs[(kf * 8 + nt) * 512 + lane * 8];
      acc[nt] = __builtin_amdgcn_mfma_f32_16x16x32_bf16(a8, bf, acc[nt], 0, 0, 0);
    }
  }
  __syncthreads();

  // stage phase B: K-steps 7..12 (6 chunks per wave)
#pragma unroll
  for (int c = 0; c < 6; ++c) {
    int ch = wv * 6 + c;
    gload_lds16(Wf + (size_t)(56 + ch) * 512 + lane * 8, &u.Bs[ch * 512]);
  }
  asm volatile("s_waitcnt vmcnt(0)" ::: "memory");
  __syncthreads();

#pragma unroll
  for (int kf = 0; kf < 6; ++kf) {
    int k0 = (kf + 7) * 32 + kg * 8;
    short8 a8;
    if (rowok && k0 + 8 <= N_ROIS) {
      float4 f0 = *(const float4*)(xp + k0);
      float4 f1 = *(const float4*)(xp + k0 + 4);
      a8[0] = (short)f2bf(f0.x); a8[1] = (short)f2bf(f0.y);
      a8[2] = (short)f2bf(f0.z); a8[3] = (short)f2bf(f0.w);
      a8[4] = (short)f2bf(f1.x); a8[5] = (short)f2bf(f1.y);
      a8[6] = (short)f2bf(f1.z); a8[7] = (short)f2bf(f1.w);
    } else {
#pragma unroll
      for (int v = 0; v < 8; ++v) {
        int k = k0 + v;
        float f = (rowok && k < N_ROIS) ? xp[k] : 0.f;
        a8[v] = (short)f2bf(f);
      }
    }
#pragma unroll
    for (int nt = 0; nt < 8; ++nt) {
      short8 bf = *(const short8*)&u.Bs[(kf * 8 + nt) * 512 + lane * 8];
      acc[nt] = __builtin_amdgcn_mfma_f32_16x16x32_bf16(a8, bf, acc[nt], 0, 0, 0);
    }
  }

#pragma unroll
  for (int r = 0; r < 4; ++r) {
    int grow = row0 + wv * 16 + kg * 4 + r;
    if (grow < N_NODES) {
      unsigned short* op = hp + (size_t)grow * HID + mrow;
#pragma unroll
      for (int nt = 0; nt < 8; ++nt) op[nt * 16] = f2bf(acc[nt][r]);
    }
  }
}

static __device__ __forceinline__ void acc8s(float* a, uint4 u, float d) {
  a[0] = fmaf(d, bf2f((unsigned short)(u.x)), a[0]);
  a[1] = fmaf(d, bf2f((unsigned short)(u.x >> 16)), a[1]);
  a[2] = fmaf(d, bf2f((unsigned short)(u.y)), a[2]);
  a[3] = fmaf(d, bf2f((unsigned short)(u.y >> 16)), a[3]);
  a[4] = fmaf(d, bf2f((unsigned short)(u.z)), a[4]);
  a[5] = fmaf(d, bf2f((unsigned short)(u.z >> 16)), a[5]);
  a[6] = fmaf(d, bf2f((unsigned short)(u.w)), a[6]);
  a[7] = fmaf(d, bf2f((unsigned short)(u.w >> 16)), a[7]);
}

// ---- aggregation (round-1 structure, measured 93 us = compulsory-miss floor):
//      16 lanes per edge-slot, dwordx4 row loads; source dinv applied here via
//      fmaf (same VALU count as the old add) ----
__global__ __launch_bounds__(256) void gather_k(
    const unsigned short* __restrict__ hp, const int* __restrict__ csr_row,
    const int* __restrict__ offs, const int* __restrict__ cnt,
    const float* __restrict__ dinv, const int* __restrict__ batch,
    const float* __restrict__ bias, unsigned int* __restrict__ pooled_bits) {
  int wave = (blockIdx.x * blockDim.x + threadIdx.x) >> 6;
  int lane = threadIdx.x & 63;
  int g  = lane >> 4;        // edge-slot group 0..3
  int cg = lane & 15;        // column group: cols cg*8 .. cg*8+7
  int n0 = wave * NPW;
  if (n0 >= N_NODES) return;
  int nend = min(n0 + NPW, N_NODES);
  float bv[8];
  {
    float4 b0 = *(const float4*)(bias + cg * 8);
    float4 b1 = *(const float4*)(bias + cg * 8 + 4);
    bv[0] = b0.x; bv[1] = b0.y; bv[2] = b0.z; bv[3] = b0.w;
    bv[4] = b1.x; bv[5] = b1.y; bv[6] = b1.z; bv[7] = b1.w;
  }
  float rm[8];
#pragma unroll
  for (int k = 0; k < 8; ++k) rm[k] = 0.f;   // relu >= 0 -> 0 is identity
  int cur_g = batch[n0];

  for (int i = n0; i < nend; ++i) {
    int start = offs[i];
    int m = cnt[i];
    float di = dinv[i];
    float a[8];
#pragma unroll
    for (int k = 0; k < 8; ++k) a[k] = 0.f;
    if (g == 0) {                         // self loop: weight dinv[i]
      uint4 u = *(const uint4*)(hp + (size_t)i * HID + cg * 8);
      acc8s(a, u, di);
    }
    for (int j = 0; j < m; j += 4) {
      int4 q = *(const int4*)(csr_row + start + j);  // wave-uniform, aligned
      int s = (g == 0) ? q.x : (g == 1) ? q.y : (g == 2) ? q.z : q.w;
      if (j + g < m) {
        float dv = dinv[s];
        uint4 u = *(const uint4*)(hp + (size_t)s * HID + cg * 8);
        acc8s(a, u, dv);
      }
    }
    // butterfly: sum the 4 edge-slot groups (lanes l, l^16, l^32, l^48)
#pragma unroll
    for (int k = 0; k < 8; ++k) {
      a[k] += __shfl_xor(a[k], 16);
      a[k] += __shfl_xor(a[k], 32);
    }
    int gb = batch[i];
    if (gb != cur_g) {                    // wave-uniform branch
      if (lane < 16) {
#pragma unroll
        for (int k = 0; k < 8; ++k)
          atomicMax(&pooled_bits[cur_g * HID + cg * 8 + k], __float_as_uint(rm[k]));
      }
#pragma unroll
      for (int k = 0; k < 8; ++k) rm[k] = 0.f;
      cur_g = gb;
    }
#pragma unroll
    for (int k = 0; k < 8; ++k)
      rm[k] = fmaxf(rm[k], fmaxf(fmaf(di, a[k], bv[k]), 0.f));
  }
  if (lane < 16) {
#pragma unroll
    for (int k = 0; k < 8; ++k)
      atomicMax(&pooled_bits[cur_g * HID + cg * 8 + k], __float_as_uint(rm[k]));
  }
}

// ---- logits = pooled @ lin_W + lin_b ----
__global__ void logits_k(const float* __restrict__ pooled, const float* __restrict__ lin_W,
                         const float* __restrict__ lin_b, float* __restrict__ out) {
  int t = blockIdx.x * blockDim.x + threadIdx.x;
  if (t < N_GRAPHS * NOUT) {
    int g = t >> 1, o = t & 1;
    float s = lin_b[o];
    const float* pg = pooled + g * HID;
#pragma unroll 8
    for (int k = 0; k < HID; ++k) s = fmaf(pg[k], lin_W[k * NOUT + o], s);
    out[t] = s;
  }
}

extern "C" void kernel_launch(void* const* d_in, const int* in_sizes, int n_in,
                              void* d_out, int out_size, void* d_ws, size_t ws_size,
                              hipStream_t stream) {
  (void)in_sizes; (void)n_in; (void)ws_size;
  const float* x     = (const float*)d_in[0];
  const int*   ei    = (const int*)d_in[1];
  const int*   row   = ei;             // sources
  const int*   col   = ei + N_EDGES;   // targets
  const int*   batch = (const int*)d_in[2];
  const float* W     = (const float*)d_in[3];
  const float* b     = (const float*)d_in[4];
  const float* lin_W = (const float*)d_in[5];
  const float* lin_b = (const float*)d_in[6];
  float* out = (float*)d_out;

  // workspace layout, 52.5 MB total. hp NO LONGER aliases pairs: csr_build
  // reads pairs concurrently with gemm writing hp in the fused L2 launch.
  // (ws_size is ample: the harness poison fill observed in rocprof is 625 MB.)
  char* ws = (char*)d_ws;
  int*   bcnt    = (int*)(ws + 0);               //   4,096 B (391 used)
  int*   offs    = (int*)(ws + 4096);            // 400,000 B
  int*   cnt     = (int*)(ws + 404096);          // 400,000 B
  float* dinv    = (float*)(ws + 804096);        // 400,000 B
  unsigned short* Wf = (unsigned short*)(ws + 1204096);   // 106,496 B (frag order)
  int*   csr_row = (int*)(ws + 1310720);         // 391*8192*4 = 12,812,288 B
  unsigned int* pairs = (unsigned int*)(ws + 14123008);   // 12,812,288 B
  unsigned short* hp  = (unsigned short*)(ws + 26935296); // 25,600,000 B (own region)

  hipMemsetAsync(bcnt, 0, NBUCK * sizeof(int), stream);
  hipMemsetAsync(d_out, 0, (size_t)out_size * sizeof(float), stream);

  // L1: bucket-append (391 blocks) || Wf fragment pack (208 blocks)
  prep_bucket_k<<<NBLK_BUCKET + NBLK_PREP, 256, 0, stream>>>(row, col, bcnt, pairs, W, Wf);
  // L2: CSR build (391 blocks, starved occupancy) || GEMM (782 blocks) on one grid
  csr_gemm_k<<<NBUCK + NBLK_GEMM, 512, 0, stream>>>(
      pairs, bcnt, csr_row, offs, cnt, dinv, x, Wf, hp);
  // L3: gather (at its compulsory-miss fabric floor ~93 us)
  {
    int waves = (N_NODES + NPW - 1) / NPW;             // 6250
    int blocks = (waves * 64 + 255) / 256;             // 1563
    gather_k<<<blocks, 256, 0, stream>>>(
        hp, csr_row, offs, cnt, dinv, batch, b,
        (unsigned int*)(out + N_GRAPHS * NOUT));
  }
  logits_k<<<(N_GRAPHS * NOUT + 255) / 256, 256, 0, stream>>>(
      out + N_GRAPHS * NOUT, lin_W, lin_b, out);
}